// Round 10
// baseline (1800.358 us; speedup 1.0000x reference)
//
#include <hip/hip_runtime.h>
#include <hip/hip_bf16.h>
#include <hip/hip_fp16.h>
#include <hip/hip_fp8.h>

// GCN: N=100000 nodes, E=1600000 edges, B=64 graphs, 20 -> 128 -> 128 -> 256.
// Strategy:
//  - gcn_conv(h,W) = (scatter_norm(h)) @ W; mean-pool commutes with W3.
//  - R1: segment starts via sorted-batch boundary detection.
//  - R2: gathers read rows pre-scaled by dinv[src].
//  - R3: CSR build as two-level bucket sort (random scatters live in LDS).
//  - R4: 16B/lane gathers; x*dinv table. Learned: random 256B-row traffic.
//  - R5: fused layer2. Learned: 32KB LDS -> 37% occ regressed.
//  - R6: layer2 @16 nodes/block (16KB LDS, full occ).
//  - R7: fp8 e4m3 gather payload. FETCH halved, time flat.
//  - R8: 16B/lane fp8. Regressed. Conclusion: gathers are bound by L2-miss
//    LINE-FILL rate (~2TB/s chip-wide on random 64B lines). Only fewer missed
//    lines (or fewer gathers) help.
//  - R9: layer-3 random gather ELIMINATED: pooled[g] = sum_j (h2[j]dinv_j) *
//    (sum_{i in g, j->i} dinv_i) + self terms. Edges re-sorted by SRC (second
//    bucket sort, (g|dinv_dst) packed per edge); k_pool3 streams h2 rows
//    sequentially and scatter-adds into a 64x128 LDS pool. Layer2 gather
//    reverted to R7's 8B/lane shape (measured best).

typedef unsigned short ushort_t;
typedef unsigned int uint_t;

constexpr int N  = 100000;
constexpr int E  = 1600000;
constexpr int B  = 64;
constexpr int IND = 20;
constexpr int HID = 128;
constexpr int OUTD = 256;

constexpr int NBUK = (N + 127) / 128;   // 782 buckets of 128 nodes
constexpr int GB   = 256;               // hist/scatter blocks
constexpr int EPB  = E / GB;            // 6250 edges per block
constexpr int BMAX = 3072;              // LDS cap per bucket (mean 2048, sd ~45)

// bf16 helpers (RNE pack, shift-unpack)
__device__ inline ushort_t f2bf(float f) {
  union { float f; uint_t u; } v; v.f = f;
  uint_t r = v.u + 0x7fffu + ((v.u >> 16) & 1u);
  return (ushort_t)(r >> 16);
}
__device__ inline float bflo(uint_t u) { return __uint_as_float(u << 16); }
__device__ inline float bfhi(uint_t u) { return __uint_as_float(u & 0xffff0000u); }

// fp8 e4m3 helpers (HW cvt on gfx950; hip_fp8.h fallback)
#if defined(__has_builtin)
#if __has_builtin(__builtin_amdgcn_cvt_f32_fp8) && __has_builtin(__builtin_amdgcn_cvt_pk_fp8_f32)
#define FP8_HW 1
#endif
#endif

template <int S>
__device__ inline float fp8dec(uint_t u) {
#ifdef FP8_HW
  return __builtin_amdgcn_cvt_f32_fp8(u, S);
#else
  __hip_fp8_storage_t b = (__hip_fp8_storage_t)((u >> (8 * S)) & 0xffu);
  __half_raw hr = __hip_cvt_fp8_to_halfraw(b, __HIP_E4M3);
  return __half2float(*(__half*)&hr);
#endif
}

template <bool W>
__device__ inline uint_t fp8pk2(float a, float b, uint_t old) {
#ifdef FP8_HW
  return __builtin_amdgcn_cvt_pk_fp8_f32(a, b, old, W);
#else
  uint_t lo = (uint_t)__hip_cvt_float_to_fp8(a, __HIP_SATFINITE, __HIP_E4M3);
  uint_t hi = (uint_t)__hip_cvt_float_to_fp8(b, __HIP_SATFINITE, __HIP_E4M3);
  uint_t pair = lo | (hi << 8);
  return W ? ((old & 0x0000ffffu) | (pair << 16)) : ((old & 0xffff0000u) | pair);
#endif
}

__device__ inline unsigned char fp8enc1(float a) {
  return (unsigned char)(fp8pk2<false>(a, a, 0u) & 0xffu);
}

// decode 8 fp8 (uint2) accumulate-style
#define FP8DEC8(u, a0, a1, a2, a3, a4, a5, a6, a7) \
  { a0 = fp8dec<0>(u.x); a1 = fp8dec<1>(u.x); a2 = fp8dec<2>(u.x); a3 = fp8dec<3>(u.x); \
    a4 = fp8dec<0>(u.y); a5 = fp8dec<1>(u.y); a6 = fp8dec<2>(u.y); a7 = fp8dec<3>(u.y); }

// ---------------- init + segment starts ----------------

__global__ __launch_bounds__(256) void k_seg_starts(const int* __restrict__ batch,
                                                    int* __restrict__ starts,
                                                    float* __restrict__ pooled) {
  int i = blockIdx.x * 256 + threadIdx.x;
  if (i < B * HID) pooled[i] = 0.f;
  if (i >= N) return;
  int b = batch[i];
  int prev = (i == 0) ? -1 : batch[i - 1];
  for (int g = prev + 1; g <= b; ++g) starts[g] = i;  // fires only at boundaries
  if (i == N - 1)
    for (int g = b + 1; g <= B; ++g) starts[g] = N;
}

// ---------------- CSR builds: bucket sorts by dst AND by src ----------------

// One pass over the edge list builds BOTH histograms (dst>>7 and src>>7).
__global__ __launch_bounds__(256) void k_hist(const int* __restrict__ eidx,
                                              int* __restrict__ histd,
                                              int* __restrict__ hists) {
  __shared__ int hd[NBUK], hs[NBUK];
  for (int i = threadIdx.x; i < NBUK; i += 256) { hd[i] = 0; hs[i] = 0; }
  __syncthreads();
  const long base = (long)blockIdx.x * EPB;
  for (int i = threadIdx.x; i < EPB; i += 256) {
    atomicAdd(&hs[eidx[base + i] >> 7], 1);
    atomicAdd(&hd[eidx[E + base + i] >> 7], 1);
  }
  __syncthreads();
  for (int i = threadIdx.x; i < NBUK; i += 256) {
    histd[(long)blockIdx.x * NBUK + i] = hd[i];
    hists[(long)blockIdx.x * NBUK + i] = hs[i];
  }
}

__global__ __launch_bounds__(256) void k_bscan(int* __restrict__ hist,
                                               int* __restrict__ btotal) {
  __shared__ int s[256];
  const int j = blockIdx.x, tid = threadIdx.x;
  int v = hist[(long)tid * NBUK + j];
  s[tid] = v;
  for (int off = 1; off < 256; off <<= 1) {
    __syncthreads();
    int x = (tid >= off) ? s[tid - off] : 0;
    __syncthreads();
    s[tid] += x;
  }
  hist[(long)tid * NBUK + j] = s[tid] - v;   // exclusive within bucket
  if (tid == 255) btotal[j] = s[255];
}

__global__ __launch_bounds__(256) void k_bktscan(const int* __restrict__ btotal,
                                                 int* __restrict__ bexcl,
                                                 int* __restrict__ rowptr) {
  __shared__ int s[256];
  int tid = threadIdx.x;
  int base = tid * 4;
  int v0 = (base + 0 < NBUK) ? btotal[base + 0] : 0;
  int v1 = (base + 1 < NBUK) ? btotal[base + 1] : 0;
  int v2 = (base + 2 < NBUK) ? btotal[base + 2] : 0;
  int v3 = (base + 3 < NBUK) ? btotal[base + 3] : 0;
  int p0 = v0, p1 = p0 + v1, p2 = p1 + v2, p3 = p2 + v3;
  s[tid] = p3;
  for (int off = 1; off < 256; off <<= 1) {
    __syncthreads();
    int x = (tid >= off) ? s[tid - off] : 0;
    __syncthreads();
    s[tid] += x;
  }
  int excl = s[tid] - p3;
  if (base + 0 < NBUK) bexcl[base + 1] = excl + p0;
  if (base + 1 < NBUK) bexcl[base + 2] = excl + p1;
  if (base + 2 < NBUK) bexcl[base + 3] = excl + p2;
  if (base + 3 < NBUK) bexcl[base + 4] = excl + p3;
  if (tid == 0) { bexcl[0] = 0; rowptr[N] = E; }
}

// dst-order scatter: payload src(20b) | dstlow(7b)<<20
__global__ __launch_bounds__(256) void k_scatter(const int* __restrict__ eidx,
                                                 const int* __restrict__ hist,
                                                 const int* __restrict__ bexcl,
                                                 int* __restrict__ ebuf) {
  __shared__ int h[NBUK];
  for (int i = threadIdx.x; i < NBUK; i += 256)
    h[i] = bexcl[i] + hist[(long)blockIdx.x * NBUK + i];
  __syncthreads();
  const long base = (long)blockIdx.x * EPB;
  for (int i = threadIdx.x; i < EPB; i += 256) {
    int srcv = eidx[base + i];
    int d = eidx[E + base + i];
    int pos = atomicAdd(&h[d >> 7], 1);
    ebuf[pos] = srcv | ((d & 127) << 20);
  }
}

// src-order scatter (AFTER k_csr so dinv is ready):
// payload srclow(7b)<<22 | batch[dst](6b)<<16 | bf16(dinv[dst])
__global__ __launch_bounds__(256) void k_scatter2(const int* __restrict__ eidx,
                                                  const int* __restrict__ hist2,
                                                  const int* __restrict__ bexcl2,
                                                  const int* __restrict__ batch,
                                                  const float* __restrict__ dinv,
                                                  int* __restrict__ ebuf2) {
  __shared__ int h[NBUK];
  for (int i = threadIdx.x; i < NBUK; i += 256)
    h[i] = bexcl2[i] + hist2[(long)blockIdx.x * NBUK + i];
  __syncthreads();
  const long base = (long)blockIdx.x * EPB;
  for (int i = threadIdx.x; i < EPB; i += 256) {
    int s = eidx[base + i];
    int d = eidx[E + base + i];
    int pos = atomicAdd(&h[s >> 7], 1);
    int w16 = f2bf(dinv[d]);                  // random 4B reads, 800KB L2-resident
    ebuf2[pos] = ((s & 127) << 22) | (batch[d] << 16) | w16;
  }
}

// One block per dst-bucket: LDS counting sort -> rowptr/dinv/colsrc, plus bf16
// x*dinv table (xs16) for the 20-dim gather.
__global__ __launch_bounds__(256) void k_csr(const int* __restrict__ ebuf,
                                             const int* __restrict__ bexcl,
                                             const float* __restrict__ x,
                                             int* __restrict__ rowptr,
                                             float* __restrict__ dinv,
                                             int* __restrict__ colsrc,
                                             ushort_t* __restrict__ xs16) {
  __shared__ int deg[128], s[128], cur[128];
  __shared__ float dv[128];
  __shared__ int lout[BMAX];
  const int j = blockIdx.x, tid = threadIdx.x;
  const int e0 = bexcl[j], e1 = bexcl[j + 1];
  const int cnt = e1 - e0;
  if (tid < 128) deg[tid] = 0;
  __syncthreads();
  for (int i = tid; i < cnt; i += 256)
    atomicAdd(&deg[(ebuf[e0 + i] >> 20) & 127], 1);
  __syncthreads();
  int v = (tid < 128) ? deg[tid] : 0;
  if (tid < 128) s[tid] = v;
  for (int off = 1; off < 128; off <<= 1) {
    __syncthreads();
    int x2 = (tid < 128 && tid >= off) ? s[tid - off] : 0;
    __syncthreads();
    if (tid < 128) s[tid] += x2;
  }
  __syncthreads();
  if (tid < 128) {
    int ex = s[tid] - v;
    cur[tid] = ex;
    float d = rsqrtf((float)(1 + v));   // deg includes self-loop
    dv[tid] = d;
    int node = j * 128 + tid;
    if (node < N) {
      rowptr[node] = e0 + ex;
      dinv[node] = d;
    }
  }
  __syncthreads();
  if (cnt <= BMAX) {
    for (int i = tid; i < cnt; i += 256) {
      int p = ebuf[e0 + i];
      int pos = atomicAdd(&cur[(p >> 20) & 127], 1);
      lout[pos] = p & 0xFFFFF;
    }
    __syncthreads();
    for (int i = tid; i < cnt; i += 256) colsrc[e0 + i] = lout[i];
  } else {  // safety fallback: direct global scatter (window still tiny -> L2)
    for (int i = tid; i < cnt; i += 256) {
      int p = ebuf[e0 + i];
      int pos = atomicAdd(&cur[(p >> 20) & 127], 1);
      colsrc[e0 + pos] = p & 0xFFFFF;
    }
  }
  // xs16 rows for this bucket (reads x coalesced, L2-warm)
  for (int idx = tid; idx < 128 * IND; idx += 256) {
    int n = idx / IND;
    long node = (long)j * 128 + n;
    if (node < N)
      xs16[node * IND + idx % IND] = f2bf(x[node * IND + idx % IND] * dv[n]);
  }
}

// ---------------- layer 1 ----------------

// 20-dim gather over bf16 x*dinv rows: 10 threads/node, 2 channels each.
__global__ __launch_bounds__(256) void k_gather20b(const ushort_t* __restrict__ xs16,
                                                   const float* __restrict__ dinv,
                                                   const int* __restrict__ rowptr,
                                                   const int* __restrict__ colsrc,
                                                   float* __restrict__ aggx) {
  int t = threadIdx.x;
  if (t >= 250) return;
  int n = t / 10, cc = (t % 10) * 2;
  long i = (long)blockIdx.x * 25 + n;               // grid = N/25 exact
  float di = dinv[i];
  uint_t u = *(const uint_t*)(xs16 + i * IND + cc);
  float a0 = bflo(u), a1 = bfhi(u);
  int e0 = rowptr[i], e1 = rowptr[i + 1];
#pragma unroll 4
  for (int e = e0; e < e1; ++e) {
    int s = colsrc[e];
    uint_t v = *(const uint_t*)(xs16 + (long)s * IND + cc);
    a0 += bflo(v); a1 += bfhi(v);
  }
  *(float2*)&aggx[i * IND + cc] = make_float2(a0 * di, a1 * di);
}

// h1 = relu(LN1(aggx@W1 + b1 + x@resW + resb));
// writes bf16(h1*dinv) (residual source) + fp8(h1*dinv) (gather payload).
__global__ __launch_bounds__(128) void k_conv1ln(const float* __restrict__ aggx,
                                                 const float* __restrict__ x,
                                                 const float* __restrict__ W1,
                                                 const float* __restrict__ b1,
                                                 const float* __restrict__ Wr,
                                                 const float* __restrict__ rb,
                                                 const float* __restrict__ g1,
                                                 const float* __restrict__ bb1,
                                                 const float* __restrict__ dinv,
                                                 ushort_t* __restrict__ h16a,
                                                 unsigned char* __restrict__ h8a) {
  __shared__ float W1s[IND * HID], Wrs[IND * HID], as[16 * IND], xs[16 * IND];
  __shared__ float Tn[16][HID];
  __shared__ float stats[16][2];
  int tid = threadIdx.x;
  for (int i = tid; i < IND * HID; i += 128) { W1s[i] = W1[i]; Wrs[i] = Wr[i]; }
  long node0 = (long)blockIdx.x * 16;                 // grid = N/16 exact
  for (int i = tid; i < 16 * IND; i += 128) {
    as[i] = aggx[node0 * IND + i];
    xs[i] = x[node0 * IND + i];
  }
  float bj = b1[tid] + rb[tid];
  __syncthreads();
  for (int n = 0; n < 16; ++n) {
    float a = bj;
#pragma unroll
    for (int k = 0; k < IND; ++k) {
      a = fmaf(as[n * IND + k], W1s[k * HID + tid], a);
      a = fmaf(xs[n * IND + k], Wrs[k * HID + tid], a);
    }
    Tn[n][tid] = a;
  }
  __syncthreads();
  {
    int n = tid >> 3, sub = tid & 7;    // 8 threads per node
    float s = 0.f, q = 0.f;
#pragma unroll
    for (int k = sub; k < HID; k += 8) { float v2 = Tn[n][k]; s += v2; q += v2 * v2; }
    s += __shfl_xor(s, 1); q += __shfl_xor(q, 1);
    s += __shfl_xor(s, 2); q += __shfl_xor(q, 2);
    s += __shfl_xor(s, 4); q += __shfl_xor(q, 4);
    if (sub == 0) {
      float mu = s * (1.f / 128.f);
      float var = q * (1.f / 128.f) - mu * mu;
      stats[n][0] = mu;
      stats[n][1] = rsqrtf(var + 1e-5f);
    }
  }
  __syncthreads();
  float gj = g1[tid], bbj = bb1[tid];
  for (int n = 0; n < 16; ++n) {
    float mu = stats[n][0], rs = stats[n][1];
    float y = fmaxf(fmaf((Tn[n][tid] - mu) * rs, gj, bbj), 0.f);
    float yd = y * dinv[node0 + n];
    h16a[(node0 + n) * HID + tid] = f2bf(yd);
    h8a[(node0 + n) * HID + tid] = fp8enc1(yd);
  }
}

// ---------------- layer 2: fused gather + GEMM + LN + ReLU (R7 shape) ----------------

__global__ __launch_bounds__(256) void k_layer2(const unsigned char* __restrict__ h8a,
                                                const ushort_t* __restrict__ h16a,
                                                const float* __restrict__ dinv,
                                                const int* __restrict__ rowptr,
                                                const int* __restrict__ colsrc,
                                                const float* __restrict__ W,
                                                const float* __restrict__ bias,
                                                const float* __restrict__ g2,
                                                const float* __restrict__ bb2,
                                                unsigned char* __restrict__ h8b) {
  __shared__ float Xs[16 * HID];     // 8 KB
  __shared__ float Wt[16 * HID];     // 8 KB
  const int tid = threadIdx.x;
  const long node0 = (long)blockIdx.x * 16;           // grid = N/16 exact
  const int lane = tid & 63, w = tid >> 6;
  const int grp = lane >> 4, l16 = lane & 15, c = l16 * 8;
  // ---- phase 1: each wave gathers 4 rows into Xs (fp8, 8B/lane) ----
  for (int r = 0; r < 4; ++r) {
    const long i = node0 + w * 4 + r;
    const float di = dinv[i];
    float a0 = 0, a1 = 0, a2 = 0, a3 = 0, a4 = 0, a5 = 0, a6 = 0, a7 = 0;
    if (grp == 0) {     // self term (row already carries dinv[i])
      uint2 u = *(const uint2*)(h8a + i * HID + c);
      FP8DEC8(u, a0, a1, a2, a3, a4, a5, a6, a7);
    }
    const int e0 = rowptr[i], e1 = rowptr[i + 1];
#pragma unroll 2
    for (int e = e0; e < e1; e += 4) {
      int idx = e + grp;
      bool valid = idx < e1;
      int s = colsrc[valid ? idx : e];
      uint2 u = *(const uint2*)(h8a + (long)s * HID + c);
      if (valid) {
        float b0, b1, b2, b3, b4, b5, b6, b7;
        FP8DEC8(u, b0, b1, b2, b3, b4, b5, b6, b7);
        a0 += b0; a1 += b1; a2 += b2; a3 += b3;
        a4 += b4; a5 += b5; a6 += b6; a7 += b7;
      }
    }
    a0 += __shfl_xor(a0, 16); a0 += __shfl_xor(a0, 32);
    a1 += __shfl_xor(a1, 16); a1 += __shfl_xor(a1, 32);
    a2 += __shfl_xor(a2, 16); a2 += __shfl_xor(a2, 32);
    a3 += __shfl_xor(a3, 16); a3 += __shfl_xor(a3, 32);
    a4 += __shfl_xor(a4, 16); a4 += __shfl_xor(a4, 32);
    a5 += __shfl_xor(a5, 16); a5 += __shfl_xor(a5, 32);
    a6 += __shfl_xor(a6, 16); a6 += __shfl_xor(a6, 32);
    a7 += __shfl_xor(a7, 16); a7 += __shfl_xor(a7, 32);
    if (grp == 0) {
      *(float4*)&Xs[(w * 4 + r) * HID + c]     = make_float4(a0 * di, a1 * di, a2 * di, a3 * di);
      *(float4*)&Xs[(w * 4 + r) * HID + c + 4] = make_float4(a4 * di, a5 * di, a6 * di, a7 * di);
    }
  }
  // ---- phase 2: GEMM Xs @ W (K-tiled in LDS, 8 tiles of 16 rows) ----
  const int nidx = tid >> 5;          // 8 nodes in flight
  const int col = (tid & 31) * 4;     // 32 threads cover 128 cols
  float4 acc[2];
  acc[0] = make_float4(0.f, 0.f, 0.f, 0.f);
  acc[1] = make_float4(0.f, 0.f, 0.f, 0.f);
  for (int kt = 0; kt < 8; ++kt) {
    __syncthreads();
    {
      const float4* wp = (const float4*)(W + kt * 16 * HID);
      float4* wd = (float4*)Wt;
      for (int i = tid; i < 16 * HID / 4; i += 256) wd[i] = wp[i];
    }
    __syncthreads();
#pragma unroll
    for (int k = 0; k < 16; k += 4) {
      float4 wv[4];
#pragma unroll
      for (int kk = 0; kk < 4; ++kk) wv[kk] = *(const float4*)&Wt[(k + kk) * HID + col];
#pragma unroll
      for (int m = 0; m < 2; ++m) {
        const int nm = nidx + m * 8;
        float4 x4 = *(const float4*)&Xs[nm * HID + kt * 16 + k];
        float xv[4] = {x4.x, x4.y, x4.z, x4.w};
#pragma unroll
        for (int kk = 0; kk < 4; ++kk) {
          acc[m].x = fmaf(xv[kk], wv[kk].x, acc[m].x);
          acc[m].y = fmaf(xv[kk], wv[kk].y, acc[m].y);
          acc[m].z = fmaf(xv[kk], wv[kk].z, acc[m].z);
          acc[m].w = fmaf(xv[kk], wv[kk].w, acc[m].w);
        }
      }
    }
  }
  // ---- phase 3: bias + residual(bf16 h16a) + LN + ReLU + fp8 store ----
  float4 bz = *(const float4*)&bias[col];
  float4 gz = *(const float4*)&g2[col];
  float4 bbz = *(const float4*)&bb2[col];
#pragma unroll
  for (int m = 0; m < 2; ++m) {
    long nm = node0 + nidx + m * 8;
    float di = dinv[nm];
    float rdi = 1.0f / di;
    uint2 ur = *(const uint2*)&h16a[nm * HID + col];
    float4 o = acc[m];
    o.x += bz.x + bflo(ur.x) * rdi; o.y += bz.y + bfhi(ur.x) * rdi;
    o.z += bz.z + bflo(ur.y) * rdi; o.w += bz.w + bfhi(ur.y) * rdi;
    float s = o.x + o.y + o.z + o.w;
    float q = o.x * o.x + o.y * o.y + o.z * o.z + o.w * o.w;
#pragma unroll
    for (int off = 1; off <= 16; off <<= 1) {   // 32-lane group = one row
      s += __shfl_xor(s, off);
      q += __shfl_xor(q, off);
    }
    float mu = s * (1.f / 128.f);
    float var = q * (1.f / 128.f) - mu * mu;
    float rs = rsqrtf(var + 1e-5f);
    float y0 = fmaxf(fmaf((o.x - mu) * rs, gz.x, bbz.x), 0.f);
    float y1 = fmaxf(fmaf((o.y - mu) * rs, gz.y, bbz.y), 0.f);
    float y2 = fmaxf(fmaf((o.z - mu) * rs, gz.z, bbz.z), 0.f);
    float y3 = fmaxf(fmaf((o.w - mu) * rs, gz.w, bbz.w), 0.f);
    uint_t p = fp8pk2<false>(y0 * di, y1 * di, 0u);
    p = fp8pk2<true>(y2 * di, y3 * di, p);
    *(uint_t*)&h8b[nm * HID + col] = p;
  }
}

// ---------------- layer 3: src-order scatter into LDS pool (NO random reads) ----------------

// One block per src-bucket. pooled[g] += w_edge * h8b_row(src), w = dinv[dst],
// plus self terms. h8b rows streamed sequentially into LDS; edge words carry
// (srclow, g, bf16 w); 64x128 fp32 pool in LDS via ds_add_f32.
__global__ __launch_bounds__(256) void k_pool3(const unsigned char* __restrict__ h8b,
                                               const int* __restrict__ bexcl2,
                                               const int* __restrict__ ebuf2,
                                               const int* __restrict__ batch,
                                               const float* __restrict__ dinv,
                                               float* __restrict__ pooled) {
  __shared__ float pool[B * HID];              // 32 KB
  __shared__ unsigned char hrow[128 * HID];    // 16 KB
  const int j = blockIdx.x, tid = threadIdx.x;
  const long nbase = (long)j * 128;
  const int validRows = min(128, N - (int)nbase);
  for (int i = tid; i < B * HID; i += 256) pool[i] = 0.f;
  {
    const uint4* src = (const uint4*)(h8b + nbase * HID);
    uint4* dst = (uint4*)hrow;
    int vtotal = validRows * HID / 16;
    for (int i = tid; i < vtotal; i += 256) dst[i] = src[i];
  }
  __syncthreads();
  const int lane = tid & 63, w = tid >> 6;
  const int c = lane * 2;
  // edges of this src-bucket (whole wave per edge; lanes cover 128 ch)
  const int e0 = bexcl2[j], e1 = bexcl2[j + 1];
  for (int e = e0 + w; e < e1; e += 4) {
    int p = ebuf2[e];                          // broadcast load
    int srcl = (p >> 22) & 127;
    int g = (p >> 16) & 63;
    float wgt = __uint_as_float((uint_t)(p & 0xffff) << 16);   // bf16 dinv[dst]
    uint_t u = *(const ushort_t*)&hrow[srcl * HID + c];
    atomicAdd(&pool[g * HID + c],     fp8dec<0>(u) * wgt);
    atomicAdd(&pool[g * HID + c + 1], fp8dec<1>(u) * wgt);
  }
  // self terms: pooled[batch[n]] += dinv[n] * row(n)   (row = h2*dinv already)
  for (int n = w; n < validRows; n += 4) {
    long node = nbase + n;
    int g = batch[node];
    float wgt = dinv[node];
    uint_t u = *(const ushort_t*)&hrow[n * HID + c];
    atomicAdd(&pool[g * HID + c],     fp8dec<0>(u) * wgt);
    atomicAdd(&pool[g * HID + c + 1], fp8dec<1>(u) * wgt);
  }
  __syncthreads();
  for (int i = tid; i < B * HID; i += 256)
    atomicAdd(&pooled[i], pool[i]);
}

// ---------------- final GEMM ----------------

// out[g] = (pooled[g]/cnt) @ W3 + b3
__global__ __launch_bounds__(256) void k_final(const float* __restrict__ pooled,
                                               const int* __restrict__ starts,
                                               const float* __restrict__ W3,
                                               const float* __restrict__ b3,
                                               float* __restrict__ out) {
  __shared__ float p[HID];
  int g = blockIdx.x, tid = threadIdx.x;
  int len = starts[g + 1] - starts[g];
  float scale = 1.0f / fmaxf((float)len, 1.0f);
  if (tid < HID) p[tid] = pooled[g * HID + tid] * scale;
  __syncthreads();
  float a = b3[tid];
  for (int k = 0; k < HID; ++k) a = fmaf(p[k], W3[k * OUTD + tid], a);
  out[g * OUTD + tid] = a;
}

// ---------------- launch ----------------

extern "C" void kernel_launch(void* const* d_in, const int* in_sizes, int n_in,
                              void* d_out, int out_size, void* d_ws, size_t ws_size,
                              hipStream_t stream) {
  const float* x    = (const float*)d_in[0];
  const int*   eidx = (const int*)d_in[1];
  const int*   batch= (const int*)d_in[2];
  const float* W1   = (const float*)d_in[3];
  const float* b1   = (const float*)d_in[4];
  const float* W2   = (const float*)d_in[5];
  const float* b2   = (const float*)d_in[6];
  const float* W3   = (const float*)d_in[7];
  const float* b3   = (const float*)d_in[8];
  const float* resW = (const float*)d_in[9];
  const float* resb = (const float*)d_in[10];
  const float* g1   = (const float*)d_in[11];
  const float* bb1  = (const float*)d_in[12];
  const float* g2   = (const float*)d_in[13];
  const float* bb2  = (const float*)d_in[14];
  float* out = (float*)d_out;

  char* w = (char*)d_ws;
  size_t off = 0;
  auto alloc = [&](size_t bytes) {
    char* p = w + off;
    off = (off + bytes + 1023) & ~(size_t)1023;
    return p;
  };
  float* dinv   = (float*)alloc((size_t)N * 4);
  int*   rowptr = (int*)alloc((size_t)(N + 1) * 4);
  int*   colsrc = (int*)alloc((size_t)E * 4);
  int*   ebuf   = (int*)alloc((size_t)E * 4);
  int*   ebuf2  = (int*)alloc((size_t)E * 4);
  int*   hist   = (int*)alloc((size_t)GB * NBUK * 4);
  int*   hist2  = (int*)alloc((size_t)GB * NBUK * 4);
  int*   btotal = (int*)alloc((size_t)NBUK * 4);
  int*   btotal2= (int*)alloc((size_t)NBUK * 4);
  int*   bexcl  = (int*)alloc((size_t)(NBUK + 1) * 4);
  int*   bexcl2 = (int*)alloc((size_t)(NBUK + 1) * 4);
  int*   starts = (int*)alloc((size_t)(B + 1) * 4);
  float* pooled = (float*)alloc((size_t)B * HID * 4);
  float* aggx   = (float*)alloc((size_t)N * IND * 4);
  ushort_t* h16a= (ushort_t*)alloc((size_t)N * HID * 2);
  ushort_t* xs16= (ushort_t*)alloc((size_t)N * IND * 2);
  unsigned char* h8a = (unsigned char*)alloc((size_t)N * HID);
  unsigned char* h8b = (unsigned char*)alloc((size_t)N * HID);

  // ---- CSR builds (dst + src order) + norm + segment starts + xs16 ----
  k_seg_starts<<<(N + 255) / 256, 256, 0, stream>>>(batch, starts, pooled);
  k_hist<<<GB, 256, 0, stream>>>(eidx, hist, hist2);
  k_bscan<<<NBUK, 256, 0, stream>>>(hist, btotal);
  k_bscan<<<NBUK, 256, 0, stream>>>(hist2, btotal2);
  k_bktscan<<<1, 256, 0, stream>>>(btotal, bexcl, rowptr);
  k_bktscan<<<1, 256, 0, stream>>>(btotal2, bexcl2, rowptr);
  k_scatter<<<GB, 256, 0, stream>>>(eidx, hist, bexcl, ebuf);
  k_csr<<<NBUK, 256, 0, stream>>>(ebuf, bexcl, x, rowptr, dinv, colsrc, xs16);
  k_scatter2<<<GB, 256, 0, stream>>>(eidx, hist2, bexcl2, batch, dinv, ebuf2);

  // ---- layer 1: 20-dim gather, conv1 + LN1 + ReLU (bf16 + fp8 out) ----
  k_gather20b<<<N / 25, 256, 0, stream>>>(xs16, dinv, rowptr, colsrc, aggx);
  k_conv1ln<<<N / 16, 128, 0, stream>>>(aggx, x, W1, b1, resW, resb,
                                        g1, bb1, dinv, h16a, h8a);

  // ---- layer 2: fp8 gather + GEMM + LN2 + ReLU (fused), fp8 out ----
  k_layer2<<<N / 16, 256, 0, stream>>>(h8a, h16a, dinv, rowptr, colsrc,
                                       W2, b2, g2, bb2, h8b);

  // ---- layer 3: src-order scatter-pool (no random reads), then 64x128x256 ----
  k_pool3<<<NBUK, 256, 0, stream>>>(h8b, bexcl2, ebuf2, batch, dinv, pooled);
  k_final<<<B, 256, 0, stream>>>(pooled, starts, W3, b3, out);
}

// Round 11
// 432.722 us; speedup vs baseline: 4.1605x; 4.1605x over previous
//
#include <hip/hip_runtime.h>
#include <hip/hip_bf16.h>
#include <hip/hip_fp16.h>
#include <hip/hip_fp8.h>

// GCN: N=100000 nodes, E=1600000 edges, B=64 graphs, 20 -> 128 -> 128 -> 256.
// Strategy:
//  - gcn_conv(h,W) = (scatter_norm(h)) @ W   (linearity) -> aggregate BEFORE the
//    transform; mean-pool commutes with W3 (pool in 128-dim, then 64x128x256).
//  - R1: segment starts via sorted-batch boundary detection.
//  - R2: gathers read rows pre-scaled by dinv[src].
//  - R3: CSR build as two-level bucket sort (random scatters live in LDS).
//  - R4: 16B/lane gathers; layer-3 gather fuses mean-pool; x*dinv table.
//    Learned: gather time pinned by random 256B-granule L3/HBM traffic.
//  - R5: fused layer2. Learned: 32KB LDS -> 37% occ -> latency-bound regressed.
//  - R6: layer2 @16 nodes/block (16KB LDS, full occ); residual from bf16 h16a.
//  - R7: fp8 e4m3 gather payload (128B rows). FETCH halved, time flat ->
//    gathers are bound by random 64B line-fill rate (~2TB/s chip-wide).
//  - R8: 16B/lane fp8 (8 edges/wave-inst). REGRESSED -> MLP is not the limiter.
//  - R9: src-order scatter-pool for layer 3. CATASTROPHIC (1.4ms): one edge
//    per wave per iteration = serial dependent chain + LDS atomic RMW + 23% occ.
//    Lesson: scatter-pools must parallelize across edges, not channels.
//  - R10: revert to R7 exactly (measured best, 434.6us). The two aggregation
//    kernels sit at the random line-fill ceiling; structure is near-roofline.

typedef unsigned short ushort_t;
typedef unsigned int uint_t;

constexpr int N  = 100000;
constexpr int E  = 1600000;
constexpr int B  = 64;
constexpr int IND = 20;
constexpr int HID = 128;
constexpr int OUTD = 256;

constexpr int NBUK = (N + 127) / 128;   // 782 buckets of 128 nodes
constexpr int GB   = 256;               // hist/scatter blocks
constexpr int EPB  = E / GB;            // 6250 edges per block
constexpr int BMAX = 3072;              // LDS cap per bucket (mean 2048, sd ~45)

// bf16 helpers (RNE pack, shift-unpack)
__device__ inline ushort_t f2bf(float f) {
  union { float f; uint_t u; } v; v.f = f;
  uint_t r = v.u + 0x7fffu + ((v.u >> 16) & 1u);
  return (ushort_t)(r >> 16);
}
__device__ inline float bflo(uint_t u) { return __uint_as_float(u << 16); }
__device__ inline float bfhi(uint_t u) { return __uint_as_float(u & 0xffff0000u); }

// fp8 e4m3 helpers (HW cvt on gfx950; hip_fp8.h fallback)
#if defined(__has_builtin)
#if __has_builtin(__builtin_amdgcn_cvt_f32_fp8) && __has_builtin(__builtin_amdgcn_cvt_pk_fp8_f32)
#define FP8_HW 1
#endif
#endif

template <int S>
__device__ inline float fp8dec(uint_t u) {
#ifdef FP8_HW
  return __builtin_amdgcn_cvt_f32_fp8(u, S);
#else
  __hip_fp8_storage_t b = (__hip_fp8_storage_t)((u >> (8 * S)) & 0xffu);
  __half_raw hr = __hip_cvt_fp8_to_halfraw(b, __HIP_E4M3);
  return __half2float(*(__half*)&hr);
#endif
}

template <bool W>
__device__ inline uint_t fp8pk2(float a, float b, uint_t old) {
#ifdef FP8_HW
  return __builtin_amdgcn_cvt_pk_fp8_f32(a, b, old, W);
#else
  uint_t lo = (uint_t)__hip_cvt_float_to_fp8(a, __HIP_SATFINITE, __HIP_E4M3);
  uint_t hi = (uint_t)__hip_cvt_float_to_fp8(b, __HIP_SATFINITE, __HIP_E4M3);
  uint_t pair = lo | (hi << 8);
  return W ? ((old & 0x0000ffffu) | (pair << 16)) : ((old & 0xffff0000u) | pair);
#endif
}

__device__ inline unsigned char fp8enc1(float a) {
  return (unsigned char)(fp8pk2<false>(a, a, 0u) & 0xffu);
}

// decode 8 fp8 (uint2) into a[0..7]
#define FP8DEC8(u, a0, a1, a2, a3, a4, a5, a6, a7) \
  { a0 = fp8dec<0>(u.x); a1 = fp8dec<1>(u.x); a2 = fp8dec<2>(u.x); a3 = fp8dec<3>(u.x); \
    a4 = fp8dec<0>(u.y); a5 = fp8dec<1>(u.y); a6 = fp8dec<2>(u.y); a7 = fp8dec<3>(u.y); }

// ---------------- init + segment starts ----------------

__global__ __launch_bounds__(256) void k_seg_starts(const int* __restrict__ batch,
                                                    int* __restrict__ starts,
                                                    float* __restrict__ pooled) {
  int i = blockIdx.x * 256 + threadIdx.x;
  if (i < B * HID) pooled[i] = 0.f;
  if (i >= N) return;
  int b = batch[i];
  int prev = (i == 0) ? -1 : batch[i - 1];
  for (int g = prev + 1; g <= b; ++g) starts[g] = i;  // fires only at boundaries
  if (i == N - 1)
    for (int g = b + 1; g <= B; ++g) starts[g] = N;
}

// ---------------- CSR build: two-level bucket sort ----------------

__global__ __launch_bounds__(256) void k_hist(const int* __restrict__ eidx,
                                              int* __restrict__ hist) {
  __shared__ int h[NBUK];
  for (int i = threadIdx.x; i < NBUK; i += 256) h[i] = 0;
  __syncthreads();
  const long base = (long)blockIdx.x * EPB;
  for (int i = threadIdx.x; i < EPB; i += 256)
    atomicAdd(&h[eidx[E + base + i] >> 7], 1);
  __syncthreads();
  for (int i = threadIdx.x; i < NBUK; i += 256)
    hist[(long)blockIdx.x * NBUK + i] = h[i];
}

__global__ __launch_bounds__(256) void k_bscan(int* __restrict__ hist,
                                               int* __restrict__ btotal) {
  __shared__ int s[256];
  const int j = blockIdx.x, tid = threadIdx.x;
  int v = hist[(long)tid * NBUK + j];
  s[tid] = v;
  for (int off = 1; off < 256; off <<= 1) {
    __syncthreads();
    int x = (tid >= off) ? s[tid - off] : 0;
    __syncthreads();
    s[tid] += x;
  }
  hist[(long)tid * NBUK + j] = s[tid] - v;   // exclusive within bucket
  if (tid == 255) btotal[j] = s[255];
}

__global__ __launch_bounds__(256) void k_bktscan(const int* __restrict__ btotal,
                                                 int* __restrict__ bexcl,
                                                 int* __restrict__ rowptr) {
  __shared__ int s[256];
  int tid = threadIdx.x;
  int base = tid * 4;
  int v0 = (base + 0 < NBUK) ? btotal[base + 0] : 0;
  int v1 = (base + 1 < NBUK) ? btotal[base + 1] : 0;
  int v2 = (base + 2 < NBUK) ? btotal[base + 2] : 0;
  int v3 = (base + 3 < NBUK) ? btotal[base + 3] : 0;
  int p0 = v0, p1 = p0 + v1, p2 = p1 + v2, p3 = p2 + v3;
  s[tid] = p3;
  for (int off = 1; off < 256; off <<= 1) {
    __syncthreads();
    int x = (tid >= off) ? s[tid - off] : 0;
    __syncthreads();
    s[tid] += x;
  }
  int excl = s[tid] - p3;
  if (base + 0 < NBUK) bexcl[base + 1] = excl + p0;
  if (base + 1 < NBUK) bexcl[base + 2] = excl + p1;
  if (base + 2 < NBUK) bexcl[base + 3] = excl + p2;
  if (base + 3 < NBUK) bexcl[base + 4] = excl + p3;
  if (tid == 0) { bexcl[0] = 0; rowptr[N] = E; }
}

__global__ __launch_bounds__(256) void k_scatter(const int* __restrict__ eidx,
                                                 const int* __restrict__ hist,
                                                 const int* __restrict__ bexcl,
                                                 int* __restrict__ ebuf) {
  __shared__ int h[NBUK];
  for (int i = threadIdx.x; i < NBUK; i += 256)
    h[i] = bexcl[i] + hist[(long)blockIdx.x * NBUK + i];
  __syncthreads();
  const long base = (long)blockIdx.x * EPB;
  for (int i = threadIdx.x; i < EPB; i += 256) {
    int srcv = eidx[base + i];
    int d = eidx[E + base + i];
    int pos = atomicAdd(&h[d >> 7], 1);
    ebuf[pos] = srcv | ((d & 127) << 20);
  }
}

// One block per bucket: LDS counting sort -> rowptr/dinv/colsrc, plus bf16
// x*dinv table (xs16) for the 20-dim gather.
__global__ __launch_bounds__(256) void k_csr(const int* __restrict__ ebuf,
                                             const int* __restrict__ bexcl,
                                             const float* __restrict__ x,
                                             int* __restrict__ rowptr,
                                             float* __restrict__ dinv,
                                             int* __restrict__ colsrc,
                                             ushort_t* __restrict__ xs16) {
  __shared__ int deg[128], s[128], cur[128];
  __shared__ float dv[128];
  __shared__ int lout[BMAX];
  const int j = blockIdx.x, tid = threadIdx.x;
  const int e0 = bexcl[j], e1 = bexcl[j + 1];
  const int cnt = e1 - e0;
  if (tid < 128) deg[tid] = 0;
  __syncthreads();
  for (int i = tid; i < cnt; i += 256)
    atomicAdd(&deg[(ebuf[e0 + i] >> 20) & 127], 1);
  __syncthreads();
  int v = (tid < 128) ? deg[tid] : 0;
  if (tid < 128) s[tid] = v;
  for (int off = 1; off < 128; off <<= 1) {
    __syncthreads();
    int x2 = (tid < 128 && tid >= off) ? s[tid - off] : 0;
    __syncthreads();
    if (tid < 128) s[tid] += x2;
  }
  __syncthreads();
  if (tid < 128) {
    int ex = s[tid] - v;
    cur[tid] = ex;
    float d = rsqrtf((float)(1 + v));   // deg includes self-loop
    dv[tid] = d;
    int node = j * 128 + tid;
    if (node < N) {
      rowptr[node] = e0 + ex;
      dinv[node] = d;
    }
  }
  __syncthreads();
  if (cnt <= BMAX) {
    for (int i = tid; i < cnt; i += 256) {
      int p = ebuf[e0 + i];
      int pos = atomicAdd(&cur[(p >> 20) & 127], 1);
      lout[pos] = p & 0xFFFFF;
    }
    __syncthreads();
    for (int i = tid; i < cnt; i += 256) colsrc[e0 + i] = lout[i];
  } else {  // safety fallback: direct global scatter (window still tiny -> L2)
    for (int i = tid; i < cnt; i += 256) {
      int p = ebuf[e0 + i];
      int pos = atomicAdd(&cur[(p >> 20) & 127], 1);
      colsrc[e0 + pos] = p & 0xFFFFF;
    }
  }
  // xs16 rows for this bucket (reads x coalesced, L2-warm)
  for (int idx = tid; idx < 128 * IND; idx += 256) {
    int n = idx / IND;
    long node = (long)j * 128 + n;
    if (node < N)
      xs16[node * IND + idx % IND] = f2bf(x[node * IND + idx % IND] * dv[n]);
  }
}

// ---------------- layer 1 ----------------

// 20-dim gather over bf16 x*dinv rows: 10 threads/node, 2 channels each.
__global__ __launch_bounds__(256) void k_gather20b(const ushort_t* __restrict__ xs16,
                                                   const float* __restrict__ dinv,
                                                   const int* __restrict__ rowptr,
                                                   const int* __restrict__ colsrc,
                                                   float* __restrict__ aggx) {
  int t = threadIdx.x;
  if (t >= 250) return;
  int n = t / 10, cc = (t % 10) * 2;
  long i = (long)blockIdx.x * 25 + n;               // grid = N/25 exact
  float di = dinv[i];
  uint_t u = *(const uint_t*)(xs16 + i * IND + cc);
  float a0 = bflo(u), a1 = bfhi(u);
  int e0 = rowptr[i], e1 = rowptr[i + 1];
#pragma unroll 4
  for (int e = e0; e < e1; ++e) {
    int s = colsrc[e];
    uint_t v = *(const uint_t*)(xs16 + (long)s * IND + cc);
    a0 += bflo(v); a1 += bfhi(v);
  }
  *(float2*)&aggx[i * IND + cc] = make_float2(a0 * di, a1 * di);
}

// h1 = relu(LN1(aggx@W1 + b1 + x@resW + resb));
// writes bf16(h1*dinv) (residual source) + fp8(h1*dinv) (gather payload).
__global__ __launch_bounds__(128) void k_conv1ln(const float* __restrict__ aggx,
                                                 const float* __restrict__ x,
                                                 const float* __restrict__ W1,
                                                 const float* __restrict__ b1,
                                                 const float* __restrict__ Wr,
                                                 const float* __restrict__ rb,
                                                 const float* __restrict__ g1,
                                                 const float* __restrict__ bb1,
                                                 const float* __restrict__ dinv,
                                                 ushort_t* __restrict__ h16a,
                                                 unsigned char* __restrict__ h8a) {
  __shared__ float W1s[IND * HID], Wrs[IND * HID], as[16 * IND], xs[16 * IND];
  __shared__ float Tn[16][HID];
  __shared__ float stats[16][2];
  int tid = threadIdx.x;
  for (int i = tid; i < IND * HID; i += 128) { W1s[i] = W1[i]; Wrs[i] = Wr[i]; }
  long node0 = (long)blockIdx.x * 16;                 // grid = N/16 exact
  for (int i = tid; i < 16 * IND; i += 128) {
    as[i] = aggx[node0 * IND + i];
    xs[i] = x[node0 * IND + i];
  }
  float bj = b1[tid] + rb[tid];
  __syncthreads();
  for (int n = 0; n < 16; ++n) {
    float a = bj;
#pragma unroll
    for (int k = 0; k < IND; ++k) {
      a = fmaf(as[n * IND + k], W1s[k * HID + tid], a);
      a = fmaf(xs[n * IND + k], Wrs[k * HID + tid], a);
    }
    Tn[n][tid] = a;
  }
  __syncthreads();
  {
    int n = tid >> 3, sub = tid & 7;    // 8 threads per node
    float s = 0.f, q = 0.f;
#pragma unroll
    for (int k = sub; k < HID; k += 8) { float v2 = Tn[n][k]; s += v2; q += v2 * v2; }
    s += __shfl_xor(s, 1); q += __shfl_xor(q, 1);
    s += __shfl_xor(s, 2); q += __shfl_xor(q, 2);
    s += __shfl_xor(s, 4); q += __shfl_xor(q, 4);
    if (sub == 0) {
      float mu = s * (1.f / 128.f);
      float var = q * (1.f / 128.f) - mu * mu;
      stats[n][0] = mu;
      stats[n][1] = rsqrtf(var + 1e-5f);
    }
  }
  __syncthreads();
  float gj = g1[tid], bbj = bb1[tid];
  for (int n = 0; n < 16; ++n) {
    float mu = stats[n][0], rs = stats[n][1];
    float y = fmaxf(fmaf((Tn[n][tid] - mu) * rs, gj, bbj), 0.f);
    float yd = y * dinv[node0 + n];
    h16a[(node0 + n) * HID + tid] = f2bf(yd);
    h8a[(node0 + n) * HID + tid] = fp8enc1(yd);
  }
}

// ---------------- layer 2: fused gather + GEMM + LN + ReLU ----------------

// 16 nodes/block, 16KB LDS -> full occupancy. Gather reads fp8 rows (128B);
// residual reconstructed from bf16 h16a via 1/dinv. Output fp8 only.
__global__ __launch_bounds__(256) void k_layer2(const unsigned char* __restrict__ h8a,
                                                const ushort_t* __restrict__ h16a,
                                                const float* __restrict__ dinv,
                                                const int* __restrict__ rowptr,
                                                const int* __restrict__ colsrc,
                                                const float* __restrict__ W,
                                                const float* __restrict__ bias,
                                                const float* __restrict__ g2,
                                                const float* __restrict__ bb2,
                                                unsigned char* __restrict__ h8b) {
  __shared__ float Xs[16 * HID];     // 8 KB
  __shared__ float Wt[16 * HID];     // 8 KB
  const int tid = threadIdx.x;
  const long node0 = (long)blockIdx.x * 16;           // grid = N/16 exact
  const int lane = tid & 63, w = tid >> 6;
  const int grp = lane >> 4, l16 = lane & 15, c = l16 * 8;
  // ---- phase 1: each wave gathers 4 rows into Xs (fp8, 8B/lane) ----
  for (int r = 0; r < 4; ++r) {
    const long i = node0 + w * 4 + r;
    const float di = dinv[i];
    float a0 = 0, a1 = 0, a2 = 0, a3 = 0, a4 = 0, a5 = 0, a6 = 0, a7 = 0;
    if (grp == 0) {     // self term (row already carries dinv[i])
      uint2 u = *(const uint2*)(h8a + i * HID + c);
      FP8DEC8(u, a0, a1, a2, a3, a4, a5, a6, a7);
    }
    const int e0 = rowptr[i], e1 = rowptr[i + 1];
#pragma unroll 2
    for (int e = e0; e < e1; e += 4) {
      int idx = e + grp;
      bool valid = idx < e1;
      int s = colsrc[valid ? idx : e];
      uint2 u = *(const uint2*)(h8a + (long)s * HID + c);
      if (valid) {
        float b0, b1, b2, b3, b4, b5, b6, b7;
        FP8DEC8(u, b0, b1, b2, b3, b4, b5, b6, b7);
        a0 += b0; a1 += b1; a2 += b2; a3 += b3;
        a4 += b4; a5 += b5; a6 += b6; a7 += b7;
      }
    }
    a0 += __shfl_xor(a0, 16); a0 += __shfl_xor(a0, 32);
    a1 += __shfl_xor(a1, 16); a1 += __shfl_xor(a1, 32);
    a2 += __shfl_xor(a2, 16); a2 += __shfl_xor(a2, 32);
    a3 += __shfl_xor(a3, 16); a3 += __shfl_xor(a3, 32);
    a4 += __shfl_xor(a4, 16); a4 += __shfl_xor(a4, 32);
    a5 += __shfl_xor(a5, 16); a5 += __shfl_xor(a5, 32);
    a6 += __shfl_xor(a6, 16); a6 += __shfl_xor(a6, 32);
    a7 += __shfl_xor(a7, 16); a7 += __shfl_xor(a7, 32);
    if (grp == 0) {
      *(float4*)&Xs[(w * 4 + r) * HID + c]     = make_float4(a0 * di, a1 * di, a2 * di, a3 * di);
      *(float4*)&Xs[(w * 4 + r) * HID + c + 4] = make_float4(a4 * di, a5 * di, a6 * di, a7 * di);
    }
  }
  // ---- phase 2: GEMM Xs @ W (K-tiled in LDS, 8 tiles of 16 rows) ----
  const int nidx = tid >> 5;          // 8 nodes in flight
  const int col = (tid & 31) * 4;     // 32 threads cover 128 cols
  float4 acc[2];
  acc[0] = make_float4(0.f, 0.f, 0.f, 0.f);
  acc[1] = make_float4(0.f, 0.f, 0.f, 0.f);
  for (int kt = 0; kt < 8; ++kt) {
    __syncthreads();
    {
      const float4* wp = (const float4*)(W + kt * 16 * HID);
      float4* wd = (float4*)Wt;
      for (int i = tid; i < 16 * HID / 4; i += 256) wd[i] = wp[i];
    }
    __syncthreads();
#pragma unroll
    for (int k = 0; k < 16; k += 4) {
      float4 wv[4];
#pragma unroll
      for (int kk = 0; kk < 4; ++kk) wv[kk] = *(const float4*)&Wt[(k + kk) * HID + col];
#pragma unroll
      for (int m = 0; m < 2; ++m) {
        const int nm = nidx + m * 8;
        float4 x4 = *(const float4*)&Xs[nm * HID + kt * 16 + k];
        float xv[4] = {x4.x, x4.y, x4.z, x4.w};
#pragma unroll
        for (int kk = 0; kk < 4; ++kk) {
          acc[m].x = fmaf(xv[kk], wv[kk].x, acc[m].x);
          acc[m].y = fmaf(xv[kk], wv[kk].y, acc[m].y);
          acc[m].z = fmaf(xv[kk], wv[kk].z, acc[m].z);
          acc[m].w = fmaf(xv[kk], wv[kk].w, acc[m].w);
        }
      }
    }
  }
  // ---- phase 3: bias + residual(bf16 h16a) + LN + ReLU + fp8 store ----
  float4 bz = *(const float4*)&bias[col];
  float4 gz = *(const float4*)&g2[col];
  float4 bbz = *(const float4*)&bb2[col];
#pragma unroll
  for (int m = 0; m < 2; ++m) {
    long nm = node0 + nidx + m * 8;
    float di = dinv[nm];
    float rdi = 1.0f / di;
    uint2 ur = *(const uint2*)&h16a[nm * HID + col];
    float4 o = acc[m];
    o.x += bz.x + bflo(ur.x) * rdi; o.y += bz.y + bfhi(ur.x) * rdi;
    o.z += bz.z + bflo(ur.y) * rdi; o.w += bz.w + bfhi(ur.y) * rdi;
    float s = o.x + o.y + o.z + o.w;
    float q = o.x * o.x + o.y * o.y + o.z * o.z + o.w * o.w;
#pragma unroll
    for (int off = 1; off <= 16; off <<= 1) {   // 32-lane group = one row
      s += __shfl_xor(s, off);
      q += __shfl_xor(q, off);
    }
    float mu = s * (1.f / 128.f);
    float var = q * (1.f / 128.f) - mu * mu;
    float rs = rsqrtf(var + 1e-5f);
    float y0 = fmaxf(fmaf((o.x - mu) * rs, gz.x, bbz.x), 0.f);
    float y1 = fmaxf(fmaf((o.y - mu) * rs, gz.y, bbz.y), 0.f);
    float y2 = fmaxf(fmaf((o.z - mu) * rs, gz.z, bbz.z), 0.f);
    float y3 = fmaxf(fmaf((o.w - mu) * rs, gz.w, bbz.w), 0.f);
    uint_t p = fp8pk2<false>(y0 * di, y1 * di, 0u);
    p = fp8pk2<true>(y2 * di, y3 * di, p);
    *(uint_t*)&h8b[nm * HID + col] = p;
  }
}

// ---------------- layer 3: fp8 gather fused with mean-pool ----------------

__global__ __launch_bounds__(256) void k_gather128p(const unsigned char* __restrict__ h8,
                                                    const float* __restrict__ dinv,
                                                    const int* __restrict__ rowptr,
                                                    const int* __restrict__ colsrc,
                                                    const int* __restrict__ batch,
                                                    float* __restrict__ pooled) {
  __shared__ float sacc[4][HID];
  __shared__ int sg[4];
  const int lane = threadIdx.x & 63;
  const int grp = lane >> 4, l16 = lane & 15;
  const int w = threadIdx.x >> 6;
  const long i = (long)blockIdx.x * 4 + w;                    // grid = N/4 exact
  const float di = dinv[i];
  const int c = l16 * 8;
  float a0 = 0, a1 = 0, a2 = 0, a3 = 0, a4 = 0, a5 = 0, a6 = 0, a7 = 0;
  if (grp == 0) {
    uint2 u = *(const uint2*)(h8 + i * HID + c);
    FP8DEC8(u, a0, a1, a2, a3, a4, a5, a6, a7);
  }
  const int e0 = rowptr[i], e1 = rowptr[i + 1];
#pragma unroll 2
  for (int e = e0; e < e1; e += 4) {
    int idx = e + grp;
    bool valid = idx < e1;
    int s = colsrc[valid ? idx : e];
    uint2 u = *(const uint2*)(h8 + (long)s * HID + c);
    if (valid) {
      float b0, b1, b2, b3, b4, b5, b6, b7;
      FP8DEC8(u, b0, b1, b2, b3, b4, b5, b6, b7);
      a0 += b0; a1 += b1; a2 += b2; a3 += b3;
      a4 += b4; a5 += b5; a6 += b6; a7 += b7;
    }
  }
  a0 += __shfl_xor(a0, 16); a0 += __shfl_xor(a0, 32);
  a1 += __shfl_xor(a1, 16); a1 += __shfl_xor(a1, 32);
  a2 += __shfl_xor(a2, 16); a2 += __shfl_xor(a2, 32);
  a3 += __shfl_xor(a3, 16); a3 += __shfl_xor(a3, 32);
  a4 += __shfl_xor(a4, 16); a4 += __shfl_xor(a4, 32);
  a5 += __shfl_xor(a5, 16); a5 += __shfl_xor(a5, 32);
  a6 += __shfl_xor(a6, 16); a6 += __shfl_xor(a6, 32);
  a7 += __shfl_xor(a7, 16); a7 += __shfl_xor(a7, 32);
  if (grp == 0) {
    *(float4*)&sacc[w][c]     = make_float4(a0 * di, a1 * di, a2 * di, a3 * di);
    *(float4*)&sacc[w][c + 4] = make_float4(a4 * di, a5 * di, a6 * di, a7 * di);
    if (l16 == 0) sg[w] = batch[i];
  }
  __syncthreads();
  if (threadIdx.x < HID) {
    int j = threadIdx.x;
    int g0 = sg[0];
    if (sg[1] == g0 && sg[2] == g0 && sg[3] == g0) {
      atomicAdd(&pooled[g0 * HID + j],
                sacc[0][j] + sacc[1][j] + sacc[2][j] + sacc[3][j]);
    } else {
#pragma unroll
      for (int w2 = 0; w2 < 4; ++w2)
        atomicAdd(&pooled[sg[w2] * HID + j], sacc[w2][j]);
    }
  }
}

// ---------------- final GEMM ----------------

// out[g] = (pooled[g]/cnt) @ W3 + b3
__global__ __launch_bounds__(256) void k_final(const float* __restrict__ pooled,
                                               const int* __restrict__ starts,
                                               const float* __restrict__ W3,
                                               const float* __restrict__ b3,
                                               float* __restrict__ out) {
  __shared__ float p[HID];
  int g = blockIdx.x, tid = threadIdx.x;
  int len = starts[g + 1] - starts[g];
  float scale = 1.0f / fmaxf((float)len, 1.0f);
  if (tid < HID) p[tid] = pooled[g * HID + tid] * scale;
  __syncthreads();
  float a = b3[tid];
  for (int k = 0; k < HID; ++k) a = fmaf(p[k], W3[k * OUTD + tid], a);
  out[g * OUTD + tid] = a;
}

// ---------------- launch ----------------

extern "C" void kernel_launch(void* const* d_in, const int* in_sizes, int n_in,
                              void* d_out, int out_size, void* d_ws, size_t ws_size,
                              hipStream_t stream) {
  const float* x    = (const float*)d_in[0];
  const int*   eidx = (const int*)d_in[1];
  const int*   batch= (const int*)d_in[2];
  const float* W1   = (const float*)d_in[3];
  const float* b1   = (const float*)d_in[4];
  const float* W2   = (const float*)d_in[5];
  const float* b2   = (const float*)d_in[6];
  const float* W3   = (const float*)d_in[7];
  const float* b3   = (const float*)d_in[8];
  const float* resW = (const float*)d_in[9];
  const float* resb = (const float*)d_in[10];
  const float* g1   = (const float*)d_in[11];
  const float* bb1  = (const float*)d_in[12];
  const float* g2   = (const float*)d_in[13];
  const float* bb2  = (const float*)d_in[14];
  float* out = (float*)d_out;

  char* w = (char*)d_ws;
  size_t off = 0;
  auto alloc = [&](size_t bytes) {
    char* p = w + off;
    off = (off + bytes + 1023) & ~(size_t)1023;
    return p;
  };
  float* dinv   = (float*)alloc((size_t)N * 4);
  int*   rowptr = (int*)alloc((size_t)(N + 1) * 4);
  int*   colsrc = (int*)alloc((size_t)E * 4);
  int*   ebuf   = (int*)alloc((size_t)E * 4);
  int*   hist   = (int*)alloc((size_t)GB * NBUK * 4);
  int*   btotal = (int*)alloc((size_t)NBUK * 4);
  int*   bexcl  = (int*)alloc((size_t)(NBUK + 1) * 4);
  int*   starts = (int*)alloc((size_t)(B + 1) * 4);
  float* pooled = (float*)alloc((size_t)B * HID * 4);
  float* aggx   = (float*)alloc((size_t)N * IND * 4);
  ushort_t* h16a= (ushort_t*)alloc((size_t)N * HID * 2);
  ushort_t* xs16= (ushort_t*)alloc((size_t)N * IND * 2);
  unsigned char* h8a = (unsigned char*)alloc((size_t)N * HID);
  unsigned char* h8b = (unsigned char*)alloc((size_t)N * HID);

  // ---- CSR (bucket sort) + norm + segment starts + xs16 ----
  k_seg_starts<<<(N + 255) / 256, 256, 0, stream>>>(batch, starts, pooled);
  k_hist<<<GB, 256, 0, stream>>>(eidx, hist);
  k_bscan<<<NBUK, 256, 0, stream>>>(hist, btotal);
  k_bktscan<<<1, 256, 0, stream>>>(btotal, bexcl, rowptr);
  k_scatter<<<GB, 256, 0, stream>>>(eidx, hist, bexcl, ebuf);
  k_csr<<<NBUK, 256, 0, stream>>>(ebuf, bexcl, x, rowptr, dinv, colsrc, xs16);

  // ---- layer 1: 20-dim gather, conv1 + LN1 + ReLU (bf16 + fp8 out) ----
  k_gather20b<<<N / 25, 256, 0, stream>>>(xs16, dinv, rowptr, colsrc, aggx);
  k_conv1ln<<<N / 16, 128, 0, stream>>>(aggx, x, W1, b1, resW, resb,
                                        g1, bb1, dinv, h16a, h8a);

  // ---- layer 2: fp8 gather + GEMM + LN2 + ReLU (fused), fp8 out ----
  k_layer2<<<N / 16, 256, 0, stream>>>(h8a, h16a, dinv, rowptr, colsrc,
                                       W2, b2, g2, bb2, h8b);

  // ---- layer 3: fp8 gather fused with mean-pool, then tiny GEMM to 256 ----
  k_gather128p<<<N / 4, 256, 0, stream>>>(h8b, dinv, rowptr, colsrc, batch, pooled);
  k_final<<<B, 256, 0, stream>>>(pooled, starts, W3, b3, out);
}

// Round 12
// 399.259 us; speedup vs baseline: 4.5093x; 1.0838x over previous
//
#include <hip/hip_runtime.h>
#include <hip/hip_bf16.h>
#include <hip/hip_fp16.h>
#include <hip/hip_fp8.h>

// GCN: N=100000 nodes, E=1600000 edges, B=64 graphs, 20 -> 128 -> 128 -> 256.
// Strategy:
//  - gcn_conv(h,W) = (scatter_norm(h)) @ W; mean-pool commutes with W3.
//  - R1: segment starts via sorted-batch boundary detection.
//  - R2: gathers read rows pre-scaled by dinv[src].
//  - R3: CSR build as two-level bucket sort (random scatters live in LDS).
//  - R4: learned: gather pinned by random-line traffic.
//  - R5: learned: 32KB LDS -> 37% occ regression.
//  - R6: layer2 fused @16 nodes/block, full occ.
//  - R7: fp8 e4m3 gather payload (measured best baseline, 433us).
//  - R8: wider loads regressed; R9: scatter-pool catastrophic (serialized).
//  - R11: layer2 GEMM moved to MFMA (v_mfma_f32_16x16x32_bf16). Phase-1 stores
//    gathered X as bf16 in LDS (A-frag = one ds_read_b128); W2 pre-packed into
//    B-fragment order (32KB, L2-hot); C via padded LDS to the LN epilogue.
//    Kills ~1300 scalar-FMA wave-insts/wave; MfmaUtil was 0.0 all session.

typedef unsigned short ushort_t;
typedef unsigned int uint_t;
typedef __attribute__((ext_vector_type(8))) short bf16x8;
typedef __attribute__((ext_vector_type(4))) float f32x4;

constexpr int N  = 100000;
constexpr int E  = 1600000;
constexpr int B  = 64;
constexpr int IND = 20;
constexpr int HID = 128;
constexpr int OUTD = 256;

constexpr int NBUK = (N + 127) / 128;   // 782 buckets of 128 nodes
constexpr int GB   = 256;               // hist/scatter blocks
constexpr int EPB  = E / GB;            // 6250 edges per block
constexpr int BMAX = 3072;              // LDS cap per bucket (mean 2048, sd ~45)

// bf16 helpers (RNE pack, shift-unpack)
__device__ inline ushort_t f2bf(float f) {
  union { float f; uint_t u; } v; v.f = f;
  uint_t r = v.u + 0x7fffu + ((v.u >> 16) & 1u);
  return (ushort_t)(r >> 16);
}
__device__ inline float bflo(uint_t u) { return __uint_as_float(u << 16); }
__device__ inline float bfhi(uint_t u) { return __uint_as_float(u & 0xffff0000u); }

// fp8 e4m3 helpers (HW cvt on gfx950; hip_fp8.h fallback)
#if defined(__has_builtin)
#if __has_builtin(__builtin_amdgcn_cvt_f32_fp8) && __has_builtin(__builtin_amdgcn_cvt_pk_fp8_f32)
#define FP8_HW 1
#endif
#endif

template <int S>
__device__ inline float fp8dec(uint_t u) {
#ifdef FP8_HW
  return __builtin_amdgcn_cvt_f32_fp8(u, S);
#else
  __hip_fp8_storage_t b = (__hip_fp8_storage_t)((u >> (8 * S)) & 0xffu);
  __half_raw hr = __hip_cvt_fp8_to_halfraw(b, __HIP_E4M3);
  return __half2float(*(__half*)&hr);
#endif
}

template <bool W>
__device__ inline uint_t fp8pk2(float a, float b, uint_t old) {
#ifdef FP8_HW
  return __builtin_amdgcn_cvt_pk_fp8_f32(a, b, old, W);
#else
  uint_t lo = (uint_t)__hip_cvt_float_to_fp8(a, __HIP_SATFINITE, __HIP_E4M3);
  uint_t hi = (uint_t)__hip_cvt_float_to_fp8(b, __HIP_SATFINITE, __HIP_E4M3);
  uint_t pair = lo | (hi << 8);
  return W ? ((old & 0x0000ffffu) | (pair << 16)) : ((old & 0xffff0000u) | pair);
#endif
}

__device__ inline unsigned char fp8enc1(float a) {
  return (unsigned char)(fp8pk2<false>(a, a, 0u) & 0xffu);
}

// decode 8 fp8 (uint2) into a[0..7]
#define FP8DEC8(u, a0, a1, a2, a3, a4, a5, a6, a7) \
  { a0 = fp8dec<0>(u.x); a1 = fp8dec<1>(u.x); a2 = fp8dec<2>(u.x); a3 = fp8dec<3>(u.x); \
    a4 = fp8dec<0>(u.y); a5 = fp8dec<1>(u.y); a6 = fp8dec<2>(u.y); a7 = fp8dec<3>(u.y); }

// ---------------- init + segment starts ----------------

__global__ __launch_bounds__(256) void k_seg_starts(const int* __restrict__ batch,
                                                    int* __restrict__ starts,
                                                    float* __restrict__ pooled) {
  int i = blockIdx.x * 256 + threadIdx.x;
  if (i < B * HID) pooled[i] = 0.f;
  if (i >= N) return;
  int b = batch[i];
  int prev = (i == 0) ? -1 : batch[i - 1];
  for (int g = prev + 1; g <= b; ++g) starts[g] = i;  // fires only at boundaries
  if (i == N - 1)
    for (int g = b + 1; g <= B; ++g) starts[g] = N;
}

// Pack W2 (fp32 [K=128][N=128]) into bf16 MFMA B-fragment order:
// entry ((t*4+kt)*64 + lane)*8 + j  <-  W[kt*32 + (lane>>4)*8 + j][t*16 + (lane&15)]
__global__ __launch_bounds__(256) void k_packW2(const float* __restrict__ W,
                                                ushort_t* __restrict__ wpack) {
  int idx = blockIdx.x * 256 + threadIdx.x;   // 64 blocks -> 16384 entries
  int j = idx & 7;
  int L = (idx >> 3) & 63;
  int kt = (idx >> 9) & 3;
  int t = idx >> 11;
  int k = kt * 32 + ((L >> 4) & 3) * 8 + j;
  int n = t * 16 + (L & 15);
  wpack[idx] = f2bf(W[k * HID + n]);
}

// ---------------- CSR build: two-level bucket sort ----------------

__global__ __launch_bounds__(256) void k_hist(const int* __restrict__ eidx,
                                              int* __restrict__ hist) {
  __shared__ int h[NBUK];
  for (int i = threadIdx.x; i < NBUK; i += 256) h[i] = 0;
  __syncthreads();
  const long base = (long)blockIdx.x * EPB;
  for (int i = threadIdx.x; i < EPB; i += 256)
    atomicAdd(&h[eidx[E + base + i] >> 7], 1);
  __syncthreads();
  for (int i = threadIdx.x; i < NBUK; i += 256)
    hist[(long)blockIdx.x * NBUK + i] = h[i];
}

__global__ __launch_bounds__(256) void k_bscan(int* __restrict__ hist,
                                               int* __restrict__ btotal) {
  __shared__ int s[256];
  const int j = blockIdx.x, tid = threadIdx.x;
  int v = hist[(long)tid * NBUK + j];
  s[tid] = v;
  for (int off = 1; off < 256; off <<= 1) {
    __syncthreads();
    int x = (tid >= off) ? s[tid - off] : 0;
    __syncthreads();
    s[tid] += x;
  }
  hist[(long)tid * NBUK + j] = s[tid] - v;   // exclusive within bucket
  if (tid == 255) btotal[j] = s[255];
}

__global__ __launch_bounds__(256) void k_bktscan(const int* __restrict__ btotal,
                                                 int* __restrict__ bexcl,
                                                 int* __restrict__ rowptr) {
  __shared__ int s[256];
  int tid = threadIdx.x;
  int base = tid * 4;
  int v0 = (base + 0 < NBUK) ? btotal[base + 0] : 0;
  int v1 = (base + 1 < NBUK) ? btotal[base + 1] : 0;
  int v2 = (base + 2 < NBUK) ? btotal[base + 2] : 0;
  int v3 = (base + 3 < NBUK) ? btotal[base + 3] : 0;
  int p0 = v0, p1 = p0 + v1, p2 = p1 + v2, p3 = p2 + v3;
  s[tid] = p3;
  for (int off = 1; off < 256; off <<= 1) {
    __syncthreads();
    int x = (tid >= off) ? s[tid - off] : 0;
    __syncthreads();
    s[tid] += x;
  }
  int excl = s[tid] - p3;
  if (base + 0 < NBUK) bexcl[base + 1] = excl + p0;
  if (base + 1 < NBUK) bexcl[base + 2] = excl + p1;
  if (base + 2 < NBUK) bexcl[base + 3] = excl + p2;
  if (base + 3 < NBUK) bexcl[base + 4] = excl + p3;
  if (tid == 0) { bexcl[0] = 0; rowptr[N] = E; }
}

__global__ __launch_bounds__(256) void k_scatter(const int* __restrict__ eidx,
                                                 const int* __restrict__ hist,
                                                 const int* __restrict__ bexcl,
                                                 int* __restrict__ ebuf) {
  __shared__ int h[NBUK];
  for (int i = threadIdx.x; i < NBUK; i += 256)
    h[i] = bexcl[i] + hist[(long)blockIdx.x * NBUK + i];
  __syncthreads();
  const long base = (long)blockIdx.x * EPB;
  for (int i = threadIdx.x; i < EPB; i += 256) {
    int srcv = eidx[base + i];
    int d = eidx[E + base + i];
    int pos = atomicAdd(&h[d >> 7], 1);
    ebuf[pos] = srcv | ((d & 127) << 20);
  }
}

// One block per bucket: LDS counting sort -> rowptr/dinv/colsrc, plus bf16
// x*dinv table (xs16) for the 20-dim gather.
__global__ __launch_bounds__(256) void k_csr(const int* __restrict__ ebuf,
                                             const int* __restrict__ bexcl,
                                             const float* __restrict__ x,
                                             int* __restrict__ rowptr,
                                             float* __restrict__ dinv,
                                             int* __restrict__ colsrc,
                                             ushort_t* __restrict__ xs16) {
  __shared__ int deg[128], s[128], cur[128];
  __shared__ float dv[128];
  __shared__ int lout[BMAX];
  const int j = blockIdx.x, tid = threadIdx.x;
  const int e0 = bexcl[j], e1 = bexcl[j + 1];
  const int cnt = e1 - e0;
  if (tid < 128) deg[tid] = 0;
  __syncthreads();
  for (int i = tid; i < cnt; i += 256)
    atomicAdd(&deg[(ebuf[e0 + i] >> 20) & 127], 1);
  __syncthreads();
  int v = (tid < 128) ? deg[tid] : 0;
  if (tid < 128) s[tid] = v;
  for (int off = 1; off < 128; off <<= 1) {
    __syncthreads();
    int x2 = (tid < 128 && tid >= off) ? s[tid - off] : 0;
    __syncthreads();
    if (tid < 128) s[tid] += x2;
  }
  __syncthreads();
  if (tid < 128) {
    int ex = s[tid] - v;
    cur[tid] = ex;
    float d = rsqrtf((float)(1 + v));   // deg includes self-loop
    dv[tid] = d;
    int node = j * 128 + tid;
    if (node < N) {
      rowptr[node] = e0 + ex;
      dinv[node] = d;
    }
  }
  __syncthreads();
  if (cnt <= BMAX) {
    for (int i = tid; i < cnt; i += 256) {
      int p = ebuf[e0 + i];
      int pos = atomicAdd(&cur[(p >> 20) & 127], 1);
      lout[pos] = p & 0xFFFFF;
    }
    __syncthreads();
    for (int i = tid; i < cnt; i += 256) colsrc[e0 + i] = lout[i];
  } else {  // safety fallback: direct global scatter (window still tiny -> L2)
    for (int i = tid; i < cnt; i += 256) {
      int p = ebuf[e0 + i];
      int pos = atomicAdd(&cur[(p >> 20) & 127], 1);
      colsrc[e0 + pos] = p & 0xFFFFF;
    }
  }
  // xs16 rows for this bucket (reads x coalesced, L2-warm)
  for (int idx = tid; idx < 128 * IND; idx += 256) {
    int n = idx / IND;
    long node = (long)j * 128 + n;
    if (node < N)
      xs16[node * IND + idx % IND] = f2bf(x[node * IND + idx % IND] * dv[n]);
  }
}

// ---------------- layer 1 ----------------

// 20-dim gather over bf16 x*dinv rows: 10 threads/node, 2 channels each.
__global__ __launch_bounds__(256) void k_gather20b(const ushort_t* __restrict__ xs16,
                                                   const float* __restrict__ dinv,
                                                   const int* __restrict__ rowptr,
                                                   const int* __restrict__ colsrc,
                                                   float* __restrict__ aggx) {
  int t = threadIdx.x;
  if (t >= 250) return;
  int n = t / 10, cc = (t % 10) * 2;
  long i = (long)blockIdx.x * 25 + n;               // grid = N/25 exact
  float di = dinv[i];
  uint_t u = *(const uint_t*)(xs16 + i * IND + cc);
  float a0 = bflo(u), a1 = bfhi(u);
  int e0 = rowptr[i], e1 = rowptr[i + 1];
#pragma unroll 4
  for (int e = e0; e < e1; ++e) {
    int s = colsrc[e];
    uint_t v = *(const uint_t*)(xs16 + (long)s * IND + cc);
    a0 += bflo(v); a1 += bfhi(v);
  }
  *(float2*)&aggx[i * IND + cc] = make_float2(a0 * di, a1 * di);
}

// h1 = relu(LN1(aggx@W1 + b1 + x@resW + resb));
// writes bf16(h1*dinv) (residual source) + fp8(h1*dinv) (gather payload).
__global__ __launch_bounds__(128) void k_conv1ln(const float* __restrict__ aggx,
                                                 const float* __restrict__ x,
                                                 const float* __restrict__ W1,
                                                 const float* __restrict__ b1,
                                                 const float* __restrict__ Wr,
                                                 const float* __restrict__ rb,
                                                 const float* __restrict__ g1,
                                                 const float* __restrict__ bb1,
                                                 const float* __restrict__ dinv,
                                                 ushort_t* __restrict__ h16a,
                                                 unsigned char* __restrict__ h8a) {
  __shared__ float W1s[IND * HID], Wrs[IND * HID], as[16 * IND], xs[16 * IND];
  __shared__ float Tn[16][HID];
  __shared__ float stats[16][2];
  int tid = threadIdx.x;
  for (int i = tid; i < IND * HID; i += 128) { W1s[i] = W1[i]; Wrs[i] = Wr[i]; }
  long node0 = (long)blockIdx.x * 16;                 // grid = N/16 exact
  for (int i = tid; i < 16 * IND; i += 128) {
    as[i] = aggx[node0 * IND + i];
    xs[i] = x[node0 * IND + i];
  }
  float bj = b1[tid] + rb[tid];
  __syncthreads();
  for (int n = 0; n < 16; ++n) {
    float a = bj;
#pragma unroll
    for (int k = 0; k < IND; ++k) {
      a = fmaf(as[n * IND + k], W1s[k * HID + tid], a);
      a = fmaf(xs[n * IND + k], Wrs[k * HID + tid], a);
    }
    Tn[n][tid] = a;
  }
  __syncthreads();
  {
    int n = tid >> 3, sub = tid & 7;    // 8 threads per node
    float s = 0.f, q = 0.f;
#pragma unroll
    for (int k = sub; k < HID; k += 8) { float v2 = Tn[n][k]; s += v2; q += v2 * v2; }
    s += __shfl_xor(s, 1); q += __shfl_xor(q, 1);
    s += __shfl_xor(s, 2); q += __shfl_xor(q, 2);
    s += __shfl_xor(s, 4); q += __shfl_xor(q, 4);
    if (sub == 0) {
      float mu = s * (1.f / 128.f);
      float var = q * (1.f / 128.f) - mu * mu;
      stats[n][0] = mu;
      stats[n][1] = rsqrtf(var + 1e-5f);
    }
  }
  __syncthreads();
  float gj = g1[tid], bbj = bb1[tid];
  for (int n = 0; n < 16; ++n) {
    float mu = stats[n][0], rs = stats[n][1];
    float y = fmaxf(fmaf((Tn[n][tid] - mu) * rs, gj, bbj), 0.f);
    float yd = y * dinv[node0 + n];
    h16a[(node0 + n) * HID + tid] = f2bf(yd);
    h8a[(node0 + n) * HID + tid] = fp8enc1(yd);
  }
}

// ---------------- layer 2: fp8 gather + MFMA GEMM + LN + ReLU ----------------

// 16 nodes/block. Phase 1: gather fp8 rows -> bf16 in LDS (A operand).
// Phase 2: v_mfma_f32_16x16x32_bf16, W2 pre-packed in B-fragment order.
// Phase 3: bias + residual(bf16 h16a) + LN + ReLU + fp8 store.
constexpr int XSTR = 136;   // bf16 stride (pad kills stride-128 bank aliasing)
constexpr int CSTR = 132;   // fp32 C stride

__global__ __launch_bounds__(256) void k_layer2(const unsigned char* __restrict__ h8a,
                                                const ushort_t* __restrict__ h16a,
                                                const float* __restrict__ dinv,
                                                const int* __restrict__ rowptr,
                                                const int* __restrict__ colsrc,
                                                const ushort_t* __restrict__ wpack,
                                                const float* __restrict__ bias,
                                                const float* __restrict__ g2,
                                                const float* __restrict__ bb2,
                                                unsigned char* __restrict__ h8b) {
  __shared__ ushort_t XsB[16 * XSTR];   // 4.25 KB bf16 gathered X
  __shared__ float Cs[16 * CSTR];       // 8.25 KB fp32 GEMM out
  const int tid = threadIdx.x;
  const long node0 = (long)blockIdx.x * 16;           // grid = N/16 exact
  const int lane = tid & 63, w = tid >> 6;
  const int grp = lane >> 4, l16 = lane & 15, c = l16 * 8;
  // ---- phase 1: each wave gathers 4 rows (fp8, 8B/lane), bf16 into XsB ----
  for (int r = 0; r < 4; ++r) {
    const long i = node0 + w * 4 + r;
    const float di = dinv[i];
    float a0 = 0, a1 = 0, a2 = 0, a3 = 0, a4 = 0, a5 = 0, a6 = 0, a7 = 0;
    if (grp == 0) {     // self term (row already carries dinv[i])
      uint2 u = *(const uint2*)(h8a + i * HID + c);
      FP8DEC8(u, a0, a1, a2, a3, a4, a5, a6, a7);
    }
    const int e0 = rowptr[i], e1 = rowptr[i + 1];
#pragma unroll 2
    for (int e = e0; e < e1; e += 4) {
      int idx = e + grp;
      bool valid = idx < e1;
      int s = colsrc[valid ? idx : e];
      uint2 u = *(const uint2*)(h8a + (long)s * HID + c);
      if (valid) {
        float b0, b1, b2, b3, b4, b5, b6, b7;
        FP8DEC8(u, b0, b1, b2, b3, b4, b5, b6, b7);
        a0 += b0; a1 += b1; a2 += b2; a3 += b3;
        a4 += b4; a5 += b5; a6 += b6; a7 += b7;
      }
    }
    a0 += __shfl_xor(a0, 16); a0 += __shfl_xor(a0, 32);
    a1 += __shfl_xor(a1, 16); a1 += __shfl_xor(a1, 32);
    a2 += __shfl_xor(a2, 16); a2 += __shfl_xor(a2, 32);
    a3 += __shfl_xor(a3, 16); a3 += __shfl_xor(a3, 32);
    a4 += __shfl_xor(a4, 16); a4 += __shfl_xor(a4, 32);
    a5 += __shfl_xor(a5, 16); a5 += __shfl_xor(a5, 32);
    a6 += __shfl_xor(a6, 16); a6 += __shfl_xor(a6, 32);
    a7 += __shfl_xor(a7, 16); a7 += __shfl_xor(a7, 32);
    if (grp == 0) {
      uint_t p0 = (uint_t)f2bf(a0 * di) | ((uint_t)f2bf(a1 * di) << 16);
      uint_t p1 = (uint_t)f2bf(a2 * di) | ((uint_t)f2bf(a3 * di) << 16);
      uint_t p2 = (uint_t)f2bf(a4 * di) | ((uint_t)f2bf(a5 * di) << 16);
      uint_t p3 = (uint_t)f2bf(a6 * di) | ((uint_t)f2bf(a7 * di) << 16);
      *(uint4*)&XsB[(w * 4 + r) * XSTR + c] = make_uint4(p0, p1, p2, p3);
    }
  }
  __syncthreads();
  // ---- phase 2: MFMA. Wave w covers n-tiles {2w, 2w+1} (cols 32w..32w+31). ----
  {
    const int arow = lane & 15, aq = lane >> 4;
    f32x4 acc0 = {0.f, 0.f, 0.f, 0.f}, acc1 = {0.f, 0.f, 0.f, 0.f};
    const int t0 = w * 2, t1 = w * 2 + 1;
#pragma unroll
    for (int kt = 0; kt < 4; ++kt) {
      bf16x8 af = *(const bf16x8*)&XsB[arow * XSTR + kt * 32 + aq * 8];
      bf16x8 b0 = *(const bf16x8*)&wpack[(t0 * 4 + kt) * 512 + lane * 8];
      bf16x8 b1 = *(const bf16x8*)&wpack[(t1 * 4 + kt) * 512 + lane * 8];
      acc0 = __builtin_amdgcn_mfma_f32_16x16x32_bf16(af, b0, acc0, 0, 0, 0);
      acc1 = __builtin_amdgcn_mfma_f32_16x16x32_bf16(af, b1, acc1, 0, 0, 0);
    }
    // C/D layout: col = lane&15, row = (lane>>4)*4 + reg
#pragma unroll
    for (int r = 0; r < 4; ++r) {
      Cs[(aq * 4 + r) * CSTR + t0 * 16 + arow] = acc0[r];
      Cs[(aq * 4 + r) * CSTR + t1 * 16 + arow] = acc1[r];
    }
  }
  __syncthreads();
  // ---- phase 3: bias + residual(bf16 h16a) + LN + ReLU + fp8 store ----
  const int nidx = tid >> 5;          // 8 nodes in flight
  const int col = (tid & 31) * 4;     // 32 threads cover 128 cols
  float4 bz = *(const float4*)&bias[col];
  float4 gz = *(const float4*)&g2[col];
  float4 bbz = *(const float4*)&bb2[col];
#pragma unroll
  for (int m = 0; m < 2; ++m) {
    int nl = nidx + m * 8;
    long nm = node0 + nl;
    float di = dinv[nm];
    float rdi = 1.0f / di;
    uint2 ur = *(const uint2*)&h16a[nm * HID + col];
    float4 o = *(const float4*)&Cs[nl * CSTR + col];
    o.x += bz.x + bflo(ur.x) * rdi; o.y += bz.y + bfhi(ur.x) * rdi;
    o.z += bz.z + bflo(ur.y) * rdi; o.w += bz.w + bfhi(ur.y) * rdi;
    float s = o.x + o.y + o.z + o.w;
    float q = o.x * o.x + o.y * o.y + o.z * o.z + o.w * o.w;
#pragma unroll
    for (int off = 1; off <= 16; off <<= 1) {   // 32-lane group = one row
      s += __shfl_xor(s, off);
      q += __shfl_xor(q, off);
    }
    float mu = s * (1.f / 128.f);
    float var = q * (1.f / 128.f) - mu * mu;
    float rs = rsqrtf(var + 1e-5f);
    float y0 = fmaxf(fmaf((o.x - mu) * rs, gz.x, bbz.x), 0.f);
    float y1 = fmaxf(fmaf((o.y - mu) * rs, gz.y, bbz.y), 0.f);
    float y2 = fmaxf(fmaf((o.z - mu) * rs, gz.z, bbz.z), 0.f);
    float y3 = fmaxf(fmaf((o.w - mu) * rs, gz.w, bbz.w), 0.f);
    uint_t p = fp8pk2<false>(y0 * di, y1 * di, 0u);
    p = fp8pk2<true>(y2 * di, y3 * di, p);
    *(uint_t*)&h8b[nm * HID + col] = p;
  }
}

// ---------------- layer 3: fp8 gather fused with mean-pool ----------------

__global__ __launch_bounds__(256) void k_gather128p(const unsigned char* __restrict__ h8,
                                                    const float* __restrict__ dinv,
                                                    const int* __restrict__ rowptr,
                                                    const int* __restrict__ colsrc,
                                                    const int* __restrict__ batch,
                                                    float* __restrict__ pooled) {
  __shared__ float sacc[4][HID];
  __shared__ int sg[4];
  const int lane = threadIdx.x & 63;
  const int grp = lane >> 4, l16 = lane & 15;
  const int w = threadIdx.x >> 6;
  const long i = (long)blockIdx.x * 4 + w;                    // grid = N/4 exact
  const float di = dinv[i];
  const int c = l16 * 8;
  float a0 = 0, a1 = 0, a2 = 0, a3 = 0, a4 = 0, a5 = 0, a6 = 0, a7 = 0;
  if (grp == 0) {
    uint2 u = *(const uint2*)(h8 + i * HID + c);
    FP8DEC8(u, a0, a1, a2, a3, a4, a5, a6, a7);
  }
  const int e0 = rowptr[i], e1 = rowptr[i + 1];
#pragma unroll 2
  for (int e = e0; e < e1; e += 4) {
    int idx = e + grp;
    bool valid = idx < e1;
    int s = colsrc[valid ? idx : e];
    uint2 u = *(const uint2*)(h8 + (long)s * HID + c);
    if (valid) {
      float b0, b1, b2, b3, b4, b5, b6, b7;
      FP8DEC8(u, b0, b1, b2, b3, b4, b5, b6, b7);
      a0 += b0; a1 += b1; a2 += b2; a3 += b3;
      a4 += b4; a5 += b5; a6 += b6; a7 += b7;
    }
  }
  a0 += __shfl_xor(a0, 16); a0 += __shfl_xor(a0, 32);
  a1 += __shfl_xor(a1, 16); a1 += __shfl_xor(a1, 32);
  a2 += __shfl_xor(a2, 16); a2 += __shfl_xor(a2, 32);
  a3 += __shfl_xor(a3, 16); a3 += __shfl_xor(a3, 32);
  a4 += __shfl_xor(a4, 16); a4 += __shfl_xor(a4, 32);
  a5 += __shfl_xor(a5, 16); a5 += __shfl_xor(a5, 32);
  a6 += __shfl_xor(a6, 16); a6 += __shfl_xor(a6, 32);
  a7 += __shfl_xor(a7, 16); a7 += __shfl_xor(a7, 32);
  if (grp == 0) {
    *(float4*)&sacc[w][c]     = make_float4(a0 * di, a1 * di, a2 * di, a3 * di);
    *(float4*)&sacc[w][c + 4] = make_float4(a4 * di, a5 * di, a6 * di, a7 * di);
    if (l16 == 0) sg[w] = batch[i];
  }
  __syncthreads();
  if (threadIdx.x < HID) {
    int j = threadIdx.x;
    int g0 = sg[0];
    if (sg[1] == g0 && sg[2] == g0 && sg[3] == g0) {
      atomicAdd(&pooled[g0 * HID + j],
                sacc[0][j] + sacc[1][j] + sacc[2][j] + sacc[3][j]);
    } else {
#pragma unroll
      for (int w2 = 0; w2 < 4; ++w2)
        atomicAdd(&pooled[sg[w2] * HID + j], sacc[w2][j]);
    }
  }
}

// ---------------- final GEMM ----------------

// out[g] = (pooled[g]/cnt) @ W3 + b3
__global__ __launch_bounds__(256) void k_final(const float* __restrict__ pooled,
                                               const int* __restrict__ starts,
                                               const float* __restrict__ W3,
                                               const float* __restrict__ b3,
                                               float* __restrict__ out) {
  __shared__ float p[HID];
  int g = blockIdx.x, tid = threadIdx.x;
  int len = starts[g + 1] - starts[g];
  float scale = 1.0f / fmaxf((float)len, 1.0f);
  if (tid < HID) p[tid] = pooled[g * HID + tid] * scale;
  __syncthreads();
  float a = b3[tid];
  for (int k = 0; k < HID; ++k) a = fmaf(p[k], W3[k * OUTD + tid], a);
  out[g * OUTD + tid] = a;
}

// ---------------- launch ----------------

extern "C" void kernel_launch(void* const* d_in, const int* in_sizes, int n_in,
                              void* d_out, int out_size, void* d_ws, size_t ws_size,
                              hipStream_t stream) {
  const float* x    = (const float*)d_in[0];
  const int*   eidx = (const int*)d_in[1];
  const int*   batch= (const int*)d_in[2];
  const float* W1   = (const float*)d_in[3];
  const float* b1   = (const float*)d_in[4];
  const float* W2   = (const float*)d_in[5];
  const float* b2   = (const float*)d_in[6];
  const float* W3   = (const float*)d_in[7];
  const float* b3   = (const float*)d_in[8];
  const float* resW = (const float*)d_in[9];
  const float* resb = (const float*)d_in[10];
  const float* g1   = (const float*)d_in[11];
  const float* bb1  = (const float*)d_in[12];
  const float* g2   = (const float*)d_in[13];
  const float* bb2  = (const float*)d_in[14];
  float* out = (float*)d_out;

  char* w = (char*)d_ws;
  size_t off = 0;
  auto alloc = [&](size_t bytes) {
    char* p = w + off;
    off = (off + bytes + 1023) & ~(size_t)1023;
    return p;
  };
  float* dinv   = (float*)alloc((size_t)N * 4);
  int*   rowptr = (int*)alloc((size_t)(N + 1) * 4);
  int*   colsrc = (int*)alloc((size_t)E * 4);
  int*   ebuf   = (int*)alloc((size_t)E * 4);
  int*   hist   = (int*)alloc((size_t)GB * NBUK * 4);
  int*   btotal = (int*)alloc((size_t)NBUK * 4);
  int*   bexcl  = (int*)alloc((size_t)(NBUK + 1) * 4);
  int*   starts = (int*)alloc((size_t)(B + 1) * 4);
  float* pooled = (float*)alloc((size_t)B * HID * 4);
  float* aggx   = (float*)alloc((size_t)N * IND * 4);
  ushort_t* h16a= (ushort_t*)alloc((size_t)N * HID * 2);
  ushort_t* xs16= (ushort_t*)alloc((size_t)N * IND * 2);
  ushort_t* wpack=(ushort_t*)alloc((size_t)HID * HID * 2);
  unsigned char* h8a = (unsigned char*)alloc((size_t)N * HID);
  unsigned char* h8b = (unsigned char*)alloc((size_t)N * HID);

  // ---- CSR (bucket sort) + norm + segment starts + xs16 + W2 pack ----
  k_seg_starts<<<(N + 255) / 256, 256, 0, stream>>>(batch, starts, pooled);
  k_packW2<<<64, 256, 0, stream>>>(W2, wpack);
  k_hist<<<GB, 256, 0, stream>>>(eidx, hist);
  k_bscan<<<NBUK, 256, 0, stream>>>(hist, btotal);
  k_bktscan<<<1, 256, 0, stream>>>(btotal, bexcl, rowptr);
  k_scatter<<<GB, 256, 0, stream>>>(eidx, hist, bexcl, ebuf);
  k_csr<<<NBUK, 256, 0, stream>>>(ebuf, bexcl, x, rowptr, dinv, colsrc, xs16);

  // ---- layer 1: 20-dim gather, conv1 + LN1 + ReLU (bf16 + fp8 out) ----
  k_gather20b<<<N / 25, 256, 0, stream>>>(xs16, dinv, rowptr, colsrc, aggx);
  k_conv1ln<<<N / 16, 128, 0, stream>>>(aggx, x, W1, b1, resW, resb,
                                        g1, bb1, dinv, h16a, h8a);

  // ---- layer 2: fp8 gather + MFMA GEMM + LN2 + ReLU (fused), fp8 out ----
  k_layer2<<<N / 16, 256, 0, stream>>>(h8a, h16a, dinv, rowptr, colsrc,
                                       wpack, b2, g2, bb2, h8b);

  // ---- layer 3: fp8 gather fused with mean-pool, then tiny GEMM to 256 ----
  k_gather128p<<<N / 4, 256, 0, stream>>>(h8b, dinv, rowptr, colsrc, batch, pooled);
  k_final<<<B, 256, 0, stream>>>(pooled, starts, W3, b3, out);
}